// Round 9
// baseline (82.016 us; speedup 1.0000x reference)
//
#include <hip/hip_runtime.h>
#include <math.h>

// Persistent blocks, 512 threads (8 waves), one walker per iteration with
// register-staged PREFETCH of the next walker's h/r under the current
// walker's compute. Wave = (spin, k-quarter); lane owns d in [4l,4l+4).
// v[16] accumulators, 16-shfl butterfly, serial pivoted 7x7 dets (t<16).

__global__ __launch_bounds__(512, 3)
void orbital_cof_kernel(const float* __restrict__ h_g,   // (B,16,256)
                        const float* __restrict__ r_g,   // (B,16,4,3)
                        const float* __restrict__ W_g,   // (2,256,8)
                        const float* __restrict__ b_g,   // (2,8)
                        const float* __restrict__ dec_g, // (2,4,8)
                        const float* __restrict__ pi_g,  // (2,4,8)
                        float* __restrict__ out,         // (2,B,8,256)
                        int nb)
{
    __shared__ float hs[16][256];    // 16 KB: current walker's h
    __shared__ float Ms[2][8][8];
    __shared__ float anti_s[16];
    __shared__ float dist_s[64];     // [s*32 + n*4 + i]

    const int t = threadIdx.x;
    const int w = t >> 6;            // 0..7
    const int l = t & 63;
    const int s  = w >> 2;           // spin
    const int kq = w & 3;            // k quarter: k = kq*2 + kk

    // ---- persistent W regs: lane covers d0=4l..+4, k = kq*2..+2 ----
    float wv[4][2];
    {
        const float* wp = W_g + s * 2048 + l * 32 + kq * 2;
#pragma unroll
        for (int dd = 0; dd < 4; ++dd) {
            float2 ww = *(const float2*)(wp + dd * 8);
            wv[dd][0] = ww.x; wv[dd][1] = ww.y;
        }
    }

    const int stride = gridDim.x;
    int b = blockIdx.x;
    if (b >= nb) return;

    // ---- prologue: prefetch walker b ----
    float4 hr0, hr1;
    float rx = 0.f, ry = 0.f, rz = 0.f;
    {
        const float4* hp = (const float4*)(h_g + (size_t)b * 4096);
        hr0 = hp[t]; hr1 = hp[t + 512];
        if (t < 64) {
            const float* rp = r_g + (size_t)b * 192 + t * 3;
            rx = rp[0]; ry = rp[1]; rz = rp[2];
        }
    }

    while (true) {
        // ---- commit prefetched walker into LDS ----
        float4* hs4 = (float4*)hs;
        hs4[t] = hr0; hs4[t + 512] = hr1;
        if (t < 64) dist_s[t] = sqrtf(rx * rx + ry * ry + rz * rz);
        __syncthreads();

        // ---- issue next walker's prefetch (hidden under compute below) ----
        const int bn = b + stride;
        if (bn < nb) {
            const float4* hp = (const float4*)(h_g + (size_t)bn * 4096);
            hr0 = hp[t]; hr1 = hp[t + 512];
            if (t < 64) {
                const float* rp = r_g + (size_t)bn * 192 + t * 3;
                rx = rp[0]; ry = rp[1]; rz = rp[2];
            }
        }

        // ---- dot: v[n*2+kk] = sum over lane's 4 d of h[n][d]*W[d][k] ----
        float v[16];
#pragma unroll
        for (int n = 0; n < 8; ++n) {
            float4 hv = *(const float4*)&hs[s * 8 + n][l * 4];
#pragma unroll
            for (int kk = 0; kk < 2; ++kk) {
                float acc = hv.x * wv[0][kk];
                acc = fmaf(hv.y, wv[1][kk], acc);
                acc = fmaf(hv.z, wv[2][kk], acc);
                acc = fmaf(hv.w, wv[3][kk], acc);
                v[n * 2 + kk] = acc;
            }
        }

        // ---- halving butterfly: masks {32,16,8,4}; lane l -> entry l>>2 ----
#pragma unroll
        for (int i = 0; i < 8; ++i) {
            float send = (l & 32) ? v[i] : v[i + 8];
            float recv = __shfl_xor(send, 32);
            v[i] = ((l & 32) ? v[i + 8] : v[i]) + recv;
        }
#pragma unroll
        for (int i = 0; i < 4; ++i) {
            float send = (l & 16) ? v[i] : v[i + 4];
            float recv = __shfl_xor(send, 16);
            v[i] = ((l & 16) ? v[i + 4] : v[i]) + recv;
        }
#pragma unroll
        for (int i = 0; i < 2; ++i) {
            float send = (l & 8) ? v[i] : v[i + 2];
            float recv = __shfl_xor(send, 8);
            v[i] = ((l & 8) ? v[i + 2] : v[i]) + recv;
        }
        {
            float send = (l & 4) ? v[0] : v[1];
            float recv = __shfl_xor(send, 4);
            v[0] = ((l & 4) ? v[1] : v[0]) + recv;
        }
        float tot = v[0];
        tot += __shfl_xor(tot, 2);
        tot += __shfl_xor(tot, 1);

        // ---- env + bias -> Ms (lanes with l&3==0 hold entry l>>2) ----
        if ((l & 3) == 0) {
            int e = l >> 2;              // n*2 + kk
            int n = e >> 1;
            int k = kq * 2 + (e & 1);
            float lin = tot + b_g[s * 8 + k];
            float env = 0.f;
#pragma unroll
            for (int i = 0; i < 4; ++i) {
                float dd = dist_s[s * 32 + n * 4 + i];
                env = fmaf(pi_g[s * 32 + i * 8 + k],
                           __expf(-dd * dec_g[s * 32 + i * 8 + k]), env);
            }
            Ms[s][n][k] = lin * env;
        }
        __syncthreads();

        // ---- 16 cofactor determinants (7x7, partial pivoting) ----
        if (t < 16) {
            int ss = t >> 3;
            int n = t & 7;
            float a[7][7];
#pragma unroll
            for (int i = 0; i < 7; ++i) {
                int src = i + (i >= n);  // skip row n
#pragma unroll
                for (int j = 0; j < 7; ++j) a[i][j] = Ms[ss][src][j + 1];  // skip col 0
            }
            float det = 1.f;
#pragma unroll
            for (int kk = 0; kk < 7; ++kk) {
#pragma unroll
                for (int i = kk + 1; i < 7; ++i) {
                    bool sw = fabsf(a[i][kk]) > fabsf(a[kk][kk]);
#pragma unroll
                    for (int j = kk; j < 7; ++j) {
                        float tk = a[kk][j], ti = a[i][j];
                        a[kk][j] = sw ? ti : tk;
                        a[i][j]  = sw ? tk : ti;
                    }
                    det = sw ? -det : det;
                }
                float piv = a[kk][kk];
                det *= piv;
                float rp = (piv != 0.f) ? (1.f / piv) : 0.f;
#pragma unroll
                for (int i = kk + 1; i < 7; ++i) {
                    float f = a[i][kk] * rp;
#pragma unroll
                    for (int j = kk + 1; j < 7; ++j) a[i][j] = fmaf(-f, a[kk][j], a[i][j]);
                }
            }
            float sgn = (n & 1) ? -1.f : 1.f;
            anti_s[t] = Ms[ss][n][0] * sgn * det;
        }
        __syncthreads();

        // ---- out = h * anti; coalesced float4 stores ----
#pragma unroll
        for (int it = 0; it < 2; ++it) {
            int f4 = t + it * 512;
            int row = f4 >> 6;           // s*8+n
            int d4 = (f4 & 63) << 2;
            float4 hv = *(const float4*)&hs[row][d4];
            float aa = anti_s[row];
            float4 o = make_float4(hv.x * aa, hv.y * aa, hv.z * aa, hv.w * aa);
            int so = row >> 3;
            int n = row & 7;
            size_t off = (size_t)so * (size_t)nb * 2048 + (size_t)b * 2048
                       + (size_t)(n * 256 + d4);
            *(float4*)(out + off) = o;
        }

        if (bn >= nb) break;
        b = bn;
        __syncthreads();                 // hs reads done -> next commit safe
    }
}

extern "C" void kernel_launch(void* const* d_in, const int* in_sizes, int n_in,
                              void* d_out, int out_size, void* d_ws, size_t ws_size,
                              hipStream_t stream) {
    int nb = in_sizes[0] / 4096;     // B = elems / (S*N*D)
    const float* h_g   = (const float*)d_in[0];
    const float* r_g   = (const float*)d_in[1];
    const float* W_g   = (const float*)d_in[2];
    const float* b_g   = (const float*)d_in[3];
    const float* dec_g = (const float*)d_in[4];
    const float* pi_g  = (const float*)d_in[5];
    int grid = 768;                  // 3 blocks/CU x 256 CU (persistent)
    if (grid > nb) grid = nb;
    orbital_cof_kernel<<<dim3(grid), dim3(512), 0, stream>>>(
        h_g, r_g, W_g, b_g, dec_g, pi_g, (float*)d_out, nb);
}

// Round 11
// 47.005 us; speedup vs baseline: 1.7448x; 1.7448x over previous
//
#include <hip/hip_runtime.h>
#include <math.h>

// One 256-thread block per walker. S=2, N=8, D=256, I=4.
// r8 structure (h staged once to LDS 16KB, register-W dot, butterfly reduce,
// pivoted serial det) + NONTEMPORAL output stores (native clang vector type):
// out is write-once, so streaming it past L2/L3 keeps h L3-resident.

typedef float f32x4 __attribute__((ext_vector_type(4)));

__global__ __launch_bounds__(256, 8)
void orbital_cof_kernel(const float* __restrict__ h_g,   // (B,16,256)
                        const float* __restrict__ r_g,   // (B,16,4,3)
                        const float* __restrict__ W_g,   // (2,256,8)
                        const float* __restrict__ b_g,   // (2,8)
                        const float* __restrict__ dec_g, // (2,4,8)
                        const float* __restrict__ pi_g,  // (2,4,8)
                        float* __restrict__ out,         // (2,B,8,256)
                        int nb)
{
    __shared__ float hs[16][256];    // 16 KB flat copy of this walker's h
    __shared__ float Ms[2][8][8];
    __shared__ float anti_s[16];
    __shared__ float dist_s[64];     // [s*32 + n*4 + i]

    const int t = threadIdx.x;
    const int b = blockIdx.x;
    const int wave = t >> 6;         // 0..3
    const int lane = t & 63;
    const int s  = wave >> 1;        // spin
    const int kh = wave & 1;         // k half

    // ---- W into registers: lane covers d0=4*lane..+4, k=kh*4..+4 ----
    float wv[4][4];
    {
        const float* wp = W_g + s * 2048 + lane * 32 + kh * 4;
#pragma unroll
        for (int dd = 0; dd < 4; ++dd) {
            float4 w = *(const float4*)(wp + dd * 8);
            wv[dd][0] = w.x; wv[dd][1] = w.y; wv[dd][2] = w.z; wv[dd][3] = w.w;
        }
    }

    // ---- stage h: flat coalesced float4 copy ----
    const float4* h4p = (const float4*)(h_g + (size_t)b * 4096);
    float4* hs4 = (float4*)hs;
#pragma unroll
    for (int it = 0; it < 4; ++it)
        hs4[t + it * 256] = h4p[t + it * 256];

    // ---- distances (t<64): t = s*32 + n*4 + i matches r layout ----
    if (t < 64) {
        const float* rp = r_g + (size_t)b * 192 + t * 3;
        float x = rp[0], y = rp[1], z = rp[2];
        dist_s[t] = sqrtf(x * x + y * y + z * z);
    }
    __syncthreads();

    // ---- dot: p[n*4+kl] = sum over lane's 4 d of h[n][d]*W[d][k] ----
    float v[32];
#pragma unroll
    for (int n = 0; n < 8; ++n) {
        float4 hv = *(const float4*)&hs[s * 8 + n][lane * 4];
#pragma unroll
        for (int kl = 0; kl < 4; ++kl) {
            float acc;
            acc = hv.x * wv[0][kl];
            acc = fmaf(hv.y, wv[1][kl], acc);
            acc = fmaf(hv.z, wv[2][kl], acc);
            acc = fmaf(hv.w, wv[3][kl], acc);
            v[n * 4 + kl] = acc;
        }
    }

    // ---- halving-butterfly reduce over 64 lanes ----
#pragma unroll
    for (int i = 0; i < 16; ++i) {
        float send = (lane & 32) ? v[i] : v[i + 16];
        float recv = __shfl_xor(send, 32);
        v[i] = ((lane & 32) ? v[i + 16] : v[i]) + recv;
    }
#pragma unroll
    for (int i = 0; i < 8; ++i) {
        float send = (lane & 16) ? v[i] : v[i + 8];
        float recv = __shfl_xor(send, 16);
        v[i] = ((lane & 16) ? v[i + 8] : v[i]) + recv;
    }
#pragma unroll
    for (int i = 0; i < 4; ++i) {
        float send = (lane & 8) ? v[i] : v[i + 4];
        float recv = __shfl_xor(send, 8);
        v[i] = ((lane & 8) ? v[i + 4] : v[i]) + recv;
    }
#pragma unroll
    for (int i = 0; i < 2; ++i) {
        float send = (lane & 4) ? v[i] : v[i + 2];
        float recv = __shfl_xor(send, 4);
        v[i] = ((lane & 4) ? v[i + 2] : v[i]) + recv;
    }
    {
        float send = (lane & 2) ? v[0] : v[1];
        float recv = __shfl_xor(send, 2);
        v[0] = ((lane & 2) ? v[1] : v[0]) + recv;
    }
    float tot = v[0] + __shfl_xor(v[0], 1);

    // ---- env + bias -> Ms (even lanes hold (n,k) = lane>>1) ----
    if ((lane & 1) == 0) {
        int idx = lane >> 1;         // n*4 + kl
        int n = idx >> 2;
        int k = kh * 4 + (idx & 3);
        float lin = tot + b_g[s * 8 + k];
        float env = 0.f;
#pragma unroll
        for (int i = 0; i < 4; ++i) {
            float dd = dist_s[s * 32 + n * 4 + i];
            env = fmaf(pi_g[s * 32 + i * 8 + k], __expf(-dd * dec_g[s * 32 + i * 8 + k]), env);
        }
        Ms[s][n][k] = lin * env;
    }
    __syncthreads();

    // ---- 16 cofactor determinants (7x7, partial pivoting, reg-resident) ----
    if (t < 16) {
        int ss = t >> 3;
        int n = t & 7;
        float a[7][7];
#pragma unroll
        for (int i = 0; i < 7; ++i) {
            int src = i + (i >= n);  // skip row n
#pragma unroll
            for (int j = 0; j < 7; ++j) a[i][j] = Ms[ss][src][j + 1];  // skip col 0
        }
        float det = 1.f;
#pragma unroll
        for (int kk = 0; kk < 7; ++kk) {
#pragma unroll
            for (int i = kk + 1; i < 7; ++i) {
                bool sw = fabsf(a[i][kk]) > fabsf(a[kk][kk]);
#pragma unroll
                for (int j = kk; j < 7; ++j) {
                    float tk = a[kk][j], ti = a[i][j];
                    a[kk][j] = sw ? ti : tk;
                    a[i][j]  = sw ? tk : ti;
                }
                det = sw ? -det : det;
            }
            float piv = a[kk][kk];
            det *= piv;
            float rp = (piv != 0.f) ? (1.f / piv) : 0.f;
#pragma unroll
            for (int i = kk + 1; i < 7; ++i) {
                float f = a[i][kk] * rp;
#pragma unroll
                for (int j = kk + 1; j < 7; ++j) a[i][j] = fmaf(-f, a[kk][j], a[i][j]);
            }
        }
        float sgn = (n & 1) ? -1.f : 1.f;
        anti_s[t] = Ms[ss][n][0] * sgn * det;
    }
    __syncthreads();

    // ---- out = h * anti; coalesced NONTEMPORAL 16B stores ----
#pragma unroll
    for (int it = 0; it < 4; ++it) {
        int f4 = t + it * 256;
        int row = f4 >> 6;           // s*8+n
        int d4 = (f4 & 63) << 2;
        float4 hv = *(const float4*)&hs[row][d4];
        float aa = anti_s[row];
        f32x4 o;
        o.x = hv.x * aa; o.y = hv.y * aa; o.z = hv.z * aa; o.w = hv.w * aa;
        int so = row >> 3;
        int n = row & 7;
        size_t off = (size_t)so * (size_t)nb * 2048 + (size_t)b * 2048 + (size_t)(n * 256 + d4);
        __builtin_nontemporal_store(o, (f32x4*)(out + off));
    }
}

extern "C" void kernel_launch(void* const* d_in, const int* in_sizes, int n_in,
                              void* d_out, int out_size, void* d_ws, size_t ws_size,
                              hipStream_t stream) {
    int nb = in_sizes[0] / 4096;     // B = elems / (S*N*D)
    const float* h_g   = (const float*)d_in[0];
    const float* r_g   = (const float*)d_in[1];
    const float* W_g   = (const float*)d_in[2];
    const float* b_g   = (const float*)d_in[3];
    const float* dec_g = (const float*)d_in[4];
    const float* pi_g  = (const float*)d_in[5];
    orbital_cof_kernel<<<dim3(nb), dim3(256), 0, stream>>>(
        h_g, r_g, W_g, b_g, dec_g, pi_g, (float*)d_out, nb);
}